// Round 1
// baseline (190.074 us; speedup 1.0000x reference)
//
#include <hip/hip_runtime.h>
#include <math.h>

#define N_PROP 1000
#define N_FG   80          // foreground classes (1..80)
#define SCORE_THRESH 0.05f
#define NMS_THRESH   0.5f
#define DET_PER_IMG  100
#define BBOX_CLIP    4.135166556742356f   // ln(1000/16)

// d_out layout (560000 floats):
//   [0, 400000)        out5: (80*1000, 5)  x1,y1,x2,y2,score
//   [400000, 480000)   labels as float
//   [480000, 560000)   final mask as 0.0/1.0
#define OUT5_OFF   0
#define LBL_OFF    400000
#define FIN_OFF    480000

// ws layout (bytes):
//   [0,4)        int   kept count
//   [4,8)        float image threshold
//   [16, 80016)  u8    keep flags [80000]
//   [80016, 400016) float compact kept scores [80000]

__global__ void init_ws(int* count) {
    if (threadIdx.x == 0) *count = 0;
}

// one block (1 wave, 64 threads) per proposal
__global__ void decode_softmax_kernel(const float* __restrict__ logits,
                                      const float* __restrict__ reg,
                                      const float* __restrict__ props,
                                      const int* __restrict__ ih,
                                      const int* __restrict__ iw,
                                      float* __restrict__ out) {
    const int n = blockIdx.x;
    const int t = threadIdx.x;   // 0..63
    const float* lrow = logits + (size_t)n * 81;

    // softmax over 81 logits (t covers 0..63, t+64 covers 64..80)
    float v0 = lrow[t];
    float v1 = (t + 64 < 81) ? lrow[t + 64] : -INFINITY;
    float m = fmaxf(v0, v1);
    for (int off = 32; off; off >>= 1) m = fmaxf(m, __shfl_down(m, off));
    m = __shfl(m, 0);
    float e0 = expf(v0 - m);
    float e1 = (t + 64 < 81) ? expf(v1 - m) : 0.0f;
    float s = e0 + e1;
    for (int off = 32; off; off >>= 1) s += __shfl_down(s, off);
    s = __shfl(s, 0);

    // proposal stats
    const float px1 = props[n * 4 + 0];
    const float py1 = props[n * 4 + 1];
    const float px2 = props[n * 4 + 2];
    const float py2 = props[n * 4 + 3];
    const float w  = px2 - px1 + 1.0f;
    const float h  = py2 - py1 + 1.0f;
    const float cx = px1 + 0.5f * w;
    const float cy = py1 + 0.5f * h;
    const float W1 = (float)iw[0] - 1.0f;
    const float H1 = (float)ih[0] - 1.0f;

    // classes 1..80: first pass cls = t+1 (t<64 -> 1..64), second cls = t+65 (t<16 -> 65..80)
    #pragma unroll
    for (int k = 0; k < 2; ++k) {
        int cls = t + 1 + k * 64;
        if (cls <= 80) {
            const float* r = reg + ((size_t)n * 81 + cls) * 4;
            float dx = r[0] / 10.0f;
            float dy = r[1] / 10.0f;
            float dw = fminf(r[2] / 5.0f, BBOX_CLIP);
            float dh = fminf(r[3] / 5.0f, BBOX_CLIP);
            float pcx = dx * w + cx;
            float pcy = dy * h + cy;
            float pw = expf(dw) * w;
            float ph = expf(dh) * h;
            float bx1 = pcx - 0.5f * pw;
            float by1 = pcy - 0.5f * ph;
            float bx2 = pcx + 0.5f * pw - 1.0f;
            float by2 = pcy + 0.5f * ph - 1.0f;
            bx1 = fminf(fmaxf(bx1, 0.0f), W1);
            bx2 = fminf(fmaxf(bx2, 0.0f), W1);
            by1 = fminf(fmaxf(by1, 0.0f), H1);
            by2 = fminf(fmaxf(by2, 0.0f), H1);
            float p = expf(lrow[cls] - m) / s;
            size_t o = ((size_t)(cls - 1) * N_PROP + n) * 5;
            out[o + 0] = bx1;
            out[o + 1] = by1;
            out[o + 2] = bx2;
            out[o + 3] = by2;
            out[o + 4] = p;
        }
    }
}

// one block (256 threads) per class: max-selection NMS (== sorted sequential NMS)
__global__ void nms_kernel(const float* __restrict__ out5,
                           unsigned char* __restrict__ keepFlags,
                           float* __restrict__ compact,
                           int* __restrict__ count) {
    const int c = blockIdx.x;     // 0..79
    const int t = threadIdx.x;    // 0..255

    __shared__ float sx1[N_PROP], sy1[N_PROP], sx2[N_PROP], sy2[N_PROP];
    __shared__ float sar[N_PROP], ssc[N_PROP];
    __shared__ unsigned char skeep[N_PROP];
    __shared__ float wv[4];
    __shared__ int   wi[4];
    __shared__ int   selIdx;
    __shared__ float sb[5];

    const float* base = out5 + (size_t)c * N_PROP * 5;

    for (int j = t; j < N_PROP; j += 256) {
        float x1 = base[j * 5 + 0];
        float y1 = base[j * 5 + 1];
        float x2 = base[j * 5 + 2];
        float y2 = base[j * 5 + 3];
        float sc = base[j * 5 + 4];
        sx1[j] = x1; sy1[j] = y1; sx2[j] = x2; sy2[j] = y2;
        sar[j] = (x2 - x1 + 1.0f) * (y2 - y1 + 1.0f);
        ssc[j] = (sc > SCORE_THRESH) ? sc : -1.0f;
        skeep[j] = 0;
    }
    __syncthreads();

    while (true) {
        // block argmax over ssc, tie-break lower index (matches stable argsort)
        float bv = -2.0f;
        int   bi = 1 << 20;
        for (int j = t; j < N_PROP; j += 256) {
            float v = ssc[j];
            if (v > bv || (v == bv && j < bi)) { bv = v; bi = j; }
        }
        for (int off = 32; off; off >>= 1) {
            float ov = __shfl_down(bv, off);
            int   oi = __shfl_down(bi, off);
            if (ov > bv || (ov == bv && oi < bi)) { bv = ov; bi = oi; }
        }
        if ((t & 63) == 0) { wv[t >> 6] = bv; wi[t >> 6] = bi; }
        __syncthreads();
        if (t == 0) {
            for (int q = 1; q < 4; ++q) {
                if (wv[q] > bv || (wv[q] == bv && wi[q] < bi)) { bv = wv[q]; bi = wi[q]; }
            }
            if (bv < 0.0f) {
                selIdx = -1;
            } else {
                selIdx = bi;
                skeep[bi] = 1;
                ssc[bi] = -1.0f;
                sb[0] = sx1[bi]; sb[1] = sy1[bi];
                sb[2] = sx2[bi]; sb[3] = sy2[bi];
                sb[4] = sar[bi];
            }
        }
        __syncthreads();
        if (selIdx == -1) break;

        const float X1 = sb[0], Y1 = sb[1], X2 = sb[2], Y2 = sb[3], A = sb[4];
        for (int j = t; j < N_PROP; j += 256) {
            if (ssc[j] >= 0.0f) {
                float iw = fminf(X2, sx2[j]) - fmaxf(X1, sx1[j]) + 1.0f;
                float ih = fminf(Y2, sy2[j]) - fmaxf(Y1, sy1[j]) + 1.0f;
                iw = fmaxf(iw, 0.0f);
                ih = fmaxf(ih, 0.0f);
                float inter = iw * ih;
                float iou = inter / (A + sar[j] - inter);
                if (iou > NMS_THRESH) ssc[j] = -1.0f;   // NaN compares false, like ref
            }
        }
        __syncthreads();
    }

    // write keep flags; compact kept scores for global top-k threshold
    for (int j = t; j < N_PROP; j += 256) {
        unsigned char k = skeep[j];
        keepFlags[c * N_PROP + j] = k;
        if (k) {
            int pos = atomicAdd(count, 1);
            compact[pos] = base[j * 5 + 4];
        }
    }
}

// single block: find 101st-largest kept score via bit-pattern binary search
__global__ void thresh_kernel(const float* __restrict__ compact,
                              const int* __restrict__ count,
                              float* __restrict__ thresh) {
    __shared__ int red[256];
    const int n = *count;
    const int t = threadIdx.x;
    if (n <= DET_PER_IMG) {
        if (t == 0) *thresh = 0.0f;   // all kept scores > 0.05 > 0 -> pass-all
        return;
    }
    unsigned lo = 0u, hi = 0x7f800000u;  // all kept scores are positive floats
    while (hi - lo > 1u) {
        unsigned mid = lo + ((hi - lo) >> 1);
        float mv = __uint_as_float(mid);
        int cnt = 0;
        for (int i = t; i < n; i += 256) cnt += (compact[i] >= mv) ? 1 : 0;
        red[t] = cnt;
        __syncthreads();
        for (int s = 128; s; s >>= 1) {
            if (t < s) red[t] += red[t + s];
            __syncthreads();
        }
        int total = red[0];
        __syncthreads();
        if (total >= DET_PER_IMG + 1) lo = mid; else hi = mid;
    }
    if (t == 0) *thresh = __uint_as_float(lo);
}

__global__ void finalize_kernel(float* __restrict__ out,
                                const unsigned char* __restrict__ keepFlags,
                                const float* __restrict__ thresh) {
    int idx = blockIdx.x * 256 + threadIdx.x;
    if (idx >= N_FG * N_PROP) return;
    const float th = *thresh;
    float sc = out[(size_t)idx * 5 + 4];
    bool fin = keepFlags[idx] && (sc >= th);
    if (!fin) {
        out[(size_t)idx * 5 + 0] = 0.0f;
        out[(size_t)idx * 5 + 1] = 0.0f;
        out[(size_t)idx * 5 + 2] = 0.0f;
        out[(size_t)idx * 5 + 3] = 0.0f;
        out[(size_t)idx * 5 + 4] = 0.0f;
    }
    int c = idx / N_PROP;
    out[LBL_OFF + idx] = fin ? (float)(c + 1) : 0.0f;
    out[FIN_OFF + idx] = fin ? 1.0f : 0.0f;
}

extern "C" void kernel_launch(void* const* d_in, const int* in_sizes, int n_in,
                              void* d_out, int out_size, void* d_ws, size_t ws_size,
                              hipStream_t stream) {
    const float* logits = (const float*)d_in[0];
    const float* reg    = (const float*)d_in[1];
    const float* props  = (const float*)d_in[2];
    const int*   ih     = (const int*)d_in[3];
    const int*   iw     = (const int*)d_in[4];
    float* out = (float*)d_out;

    char* ws = (char*)d_ws;
    int*   count   = (int*)(ws + 0);
    float* thresh  = (float*)(ws + 4);
    unsigned char* keepFlags = (unsigned char*)(ws + 16);
    float* compact = (float*)(ws + 80016);

    init_ws<<<1, 64, 0, stream>>>(count);
    decode_softmax_kernel<<<N_PROP, 64, 0, stream>>>(logits, reg, props, ih, iw, out);
    nms_kernel<<<N_FG, 256, 0, stream>>>(out, keepFlags, compact, count);
    thresh_kernel<<<1, 256, 0, stream>>>(compact, count, thresh);
    finalize_kernel<<<(N_FG * N_PROP + 255) / 256, 256, 0, stream>>>(out, keepFlags, thresh);
}

// Round 2
// 80.317 us; speedup vs baseline: 2.3666x; 2.3666x over previous
//
#include <hip/hip_runtime.h>
#include <math.h>

#define N_PROP 1000
#define N_FG   80          // foreground classes (1..80)
#define SCORE_THRESH 0.05f
#define NMS_THRESH   0.5f
#define DET_PER_IMG  100
#define BBOX_CLIP    4.135166556742356f   // ln(1000/16)

// d_out layout (560000 floats):
//   [0, 400000)        out5: (80*1000, 5)  x1,y1,x2,y2,score
//   [400000, 480000)   labels as float
//   [480000, 560000)   final mask as 0.0/1.0
#define LBL_OFF    400000
#define FIN_OFF    480000

// ws layout (bytes):
//   [0,4)        int   kept count
//   [4,8)        float image threshold
//   [16, 80016)  u8    keep flags [80000]
//   [80016, 400016) float compact kept scores [80000]

// one block (1 wave, 64 threads) per proposal; block 0 also zeroes the counter
__global__ __launch_bounds__(64)
void decode_softmax_kernel(const float* __restrict__ logits,
                           const float* __restrict__ reg,
                           const float* __restrict__ props,
                           const int* __restrict__ ih,
                           const int* __restrict__ iw,
                           float* __restrict__ out,
                           int* __restrict__ count) {
    const int n = blockIdx.x;
    const int t = threadIdx.x;   // 0..63
    if (n == 0 && t == 0) *count = 0;
    const float* lrow = logits + (size_t)n * 81;

    // softmax over 81 logits (t covers 0..63, t+64 covers 64..80)
    float v0 = lrow[t];
    float v1 = (t + 64 < 81) ? lrow[t + 64] : -INFINITY;
    float m = fmaxf(v0, v1);
    for (int off = 32; off; off >>= 1) m = fmaxf(m, __shfl_down(m, off));
    m = __shfl(m, 0);
    float e0 = expf(v0 - m);
    float e1 = (t + 64 < 81) ? expf(v1 - m) : 0.0f;
    float s = e0 + e1;
    for (int off = 32; off; off >>= 1) s += __shfl_down(s, off);
    s = __shfl(s, 0);

    // proposal stats
    const float px1 = props[n * 4 + 0];
    const float py1 = props[n * 4 + 1];
    const float px2 = props[n * 4 + 2];
    const float py2 = props[n * 4 + 3];
    const float w  = px2 - px1 + 1.0f;
    const float h  = py2 - py1 + 1.0f;
    const float cx = px1 + 0.5f * w;
    const float cy = py1 + 0.5f * h;
    const float W1 = (float)iw[0] - 1.0f;
    const float H1 = (float)ih[0] - 1.0f;

    #pragma unroll
    for (int k = 0; k < 2; ++k) {
        int cls = t + 1 + k * 64;
        if (cls <= 80) {
            const float* r = reg + ((size_t)n * 81 + cls) * 4;
            float dx = r[0] / 10.0f;
            float dy = r[1] / 10.0f;
            float dw = fminf(r[2] / 5.0f, BBOX_CLIP);
            float dh = fminf(r[3] / 5.0f, BBOX_CLIP);
            float pcx = dx * w + cx;
            float pcy = dy * h + cy;
            float pw = expf(dw) * w;
            float ph = expf(dh) * h;
            float bx1 = pcx - 0.5f * pw;
            float by1 = pcy - 0.5f * ph;
            float bx2 = pcx + 0.5f * pw - 1.0f;
            float by2 = pcy + 0.5f * ph - 1.0f;
            bx1 = fminf(fmaxf(bx1, 0.0f), W1);
            bx2 = fminf(fmaxf(bx2, 0.0f), W1);
            by1 = fminf(fmaxf(by1, 0.0f), H1);
            by2 = fminf(fmaxf(by2, 0.0f), H1);
            float p = expf(lrow[cls] - m) / s;
            size_t o = ((size_t)(cls - 1) * N_PROP + n) * 5;
            out[o + 0] = bx1;
            out[o + 1] = by1;
            out[o + 2] = bx2;
            out[o + 3] = by2;
            out[o + 4] = p;
        }
    }
}

// one block (1 wave, 64 threads) per class:
// compact valid -> rank-sort -> sequential suppression over sorted list
__global__ __launch_bounds__(64)
void nms_kernel(const float* __restrict__ out5,
                unsigned char* __restrict__ keepFlags,
                float* __restrict__ compact,
                int* __restrict__ count) {
    const int c = blockIdx.x;     // 0..79
    const int lane = threadIdx.x; // 0..63

    __shared__ float vssc[N_PROP];
    __shared__ int   vsidx[N_PROP];
    __shared__ int   spos[N_PROP];
    __shared__ float sx1[N_PROP], sy1[N_PROP], sx2[N_PROP], sy2[N_PROP];
    __shared__ float sar[N_PROP], ssc2[N_PROP];
    __shared__ int   sjdx[N_PROP];
    __shared__ unsigned char skeep[N_PROP];

    const float* base = out5 + (size_t)c * N_PROP * 5;

    // phase 1: compact valid entries (score > thresh), preserving index order
    int V = 0;
    #pragma unroll
    for (int it = 0; it < 16; ++it) {
        int j = it * 64 + lane;
        float sc = -1.0f;
        bool val = false;
        if (j < N_PROP) {
            sc = base[(size_t)j * 5 + 4];
            val = sc > SCORE_THRESH;
        }
        unsigned long long mask = __ballot(val);
        int pre = __popcll(mask & ((1ULL << lane) - 1ULL));
        if (val) { vssc[V + pre] = sc; vsidx[V + pre] = j; }
        V += __popcll(mask);
    }
    __syncthreads();

    // phase 2: stable descending rank (ties -> lower original index first)
    for (int v = lane; v < V; v += 64) {
        float s = vssc[v];
        int id = vsidx[v];
        int r = 0;
        for (int u = 0; u < V; ++u) {
            float su = vssc[u];
            r += (su > s) || (su == s && vsidx[u] < id);
        }
        spos[v] = r;
    }
    __syncthreads();

    // phase 3: gather boxes into sorted slots
    for (int v = lane; v < V; v += 64) {
        int r = spos[v];
        int j = vsidx[v];
        const float* bp = base + (size_t)j * 5;
        float x1 = bp[0], y1 = bp[1], x2 = bp[2], y2 = bp[3];
        sx1[r] = x1; sy1[r] = y1; sx2[r] = x2; sy2[r] = y2;
        sar[r] = (x2 - x1 + 1.0f) * (y2 - y1 + 1.0f);
        ssc2[r] = vssc[v];
        sjdx[r] = j;
        skeep[r] = 1;
    }
    __syncthreads();

    // phase 4: sequential suppression (exactly the reference's sorted scan)
    for (int r = 0; r < V; ++r) {
        bool alive = skeep[r] != 0;   // uniform across lanes
        if (alive) {
            const float X1 = sx1[r], Y1 = sy1[r], X2 = sx2[r], Y2 = sy2[r], A = sar[r];
            for (int v = r + 1 + lane; v < V; v += 64) {
                if (skeep[v]) {
                    float iw = fminf(X2, sx2[v]) - fmaxf(X1, sx1[v]) + 1.0f;
                    float ihh = fminf(Y2, sy2[v]) - fmaxf(Y1, sy1[v]) + 1.0f;
                    iw = fmaxf(iw, 0.0f);
                    ihh = fmaxf(ihh, 0.0f);
                    float inter = iw * ihh;
                    float iou = inter / (A + sar[v] - inter);
                    if (iou > NMS_THRESH) skeep[v] = 0;   // NaN compares false, like ref
                }
            }
        }
        __syncthreads();
    }

    // phase 5: write keep flags + compact kept scores
    for (int j = lane; j < N_PROP; j += 64) keepFlags[c * N_PROP + j] = 0;
    __syncthreads();
    for (int r = lane; r < V; r += 64) {
        if (skeep[r]) {
            keepFlags[c * N_PROP + sjdx[r]] = 1;
            int pos = atomicAdd(count, 1);
            compact[pos] = ssc2[r];
        }
    }
}

// single wave: 101st-largest kept score via bit-pattern binary search in LDS
__global__ __launch_bounds__(64)
void thresh_kernel(const float* __restrict__ compact,
                   const int* __restrict__ count,
                   float* __restrict__ thresh) {
    __shared__ float ls[8192];
    const int n = *count;
    const int lane = threadIdx.x;
    if (n <= DET_PER_IMG) {
        if (lane == 0) *thresh = 0.0f;   // kept scores all > 0.05 > 0 -> pass-all
        return;
    }
    const bool useL = (n <= 8192);
    if (useL) {
        for (int i = lane; i < n; i += 64) ls[i] = compact[i];
    }
    __syncthreads();
    unsigned lo = 0u, hi = 0x40000000u;  // scores are in (0.05, 1.0]
    while (hi - lo > 1u) {
        unsigned mid = lo + ((hi - lo) >> 1);
        float mv = __uint_as_float(mid);
        int cnt = 0;
        if (useL) {
            for (int i = lane; i < n; i += 64) cnt += (ls[i] >= mv) ? 1 : 0;
        } else {
            for (int i = lane; i < n; i += 64) cnt += (compact[i] >= mv) ? 1 : 0;
        }
        for (int off = 32; off; off >>= 1) cnt += __shfl_down(cnt, off);
        cnt = __shfl(cnt, 0);
        if (cnt >= DET_PER_IMG + 1) lo = mid; else hi = mid;
    }
    if (lane == 0) *thresh = __uint_as_float(lo);
}

__global__ __launch_bounds__(256)
void finalize_kernel(float* __restrict__ out,
                     const unsigned char* __restrict__ keepFlags,
                     const float* __restrict__ thresh) {
    int idx = blockIdx.x * 256 + threadIdx.x;
    if (idx >= N_FG * N_PROP) return;
    const float th = *thresh;
    float sc = out[(size_t)idx * 5 + 4];
    bool fin = keepFlags[idx] && (sc >= th);
    if (!fin) {
        out[(size_t)idx * 5 + 0] = 0.0f;
        out[(size_t)idx * 5 + 1] = 0.0f;
        out[(size_t)idx * 5 + 2] = 0.0f;
        out[(size_t)idx * 5 + 3] = 0.0f;
        out[(size_t)idx * 5 + 4] = 0.0f;
    }
    int c = idx / N_PROP;
    out[LBL_OFF + idx] = fin ? (float)(c + 1) : 0.0f;
    out[FIN_OFF + idx] = fin ? 1.0f : 0.0f;
}

extern "C" void kernel_launch(void* const* d_in, const int* in_sizes, int n_in,
                              void* d_out, int out_size, void* d_ws, size_t ws_size,
                              hipStream_t stream) {
    const float* logits = (const float*)d_in[0];
    const float* reg    = (const float*)d_in[1];
    const float* props  = (const float*)d_in[2];
    const int*   ih     = (const int*)d_in[3];
    const int*   iw     = (const int*)d_in[4];
    float* out = (float*)d_out;

    char* ws = (char*)d_ws;
    int*   count   = (int*)(ws + 0);
    float* thresh  = (float*)(ws + 4);
    unsigned char* keepFlags = (unsigned char*)(ws + 16);
    float* compact = (float*)(ws + 80016);

    decode_softmax_kernel<<<N_PROP, 64, 0, stream>>>(logits, reg, props, ih, iw, out, count);
    nms_kernel<<<N_FG, 64, 0, stream>>>(out, keepFlags, compact, count);
    thresh_kernel<<<1, 64, 0, stream>>>(compact, count, thresh);
    finalize_kernel<<<(N_FG * N_PROP + 255) / 256, 256, 0, stream>>>(out, keepFlags, thresh);
}